// Round 10
// baseline (276.435 us; speedup 1.0000x reference)
//
#include <hip/hip_runtime.h>

// SparseDIA (9 static offsets) @ dense: out[r,c] = sum_k diags[k, r+off_k] * other[r+off_k, c]
// N=8192, M=4096, fp32.
//
// R4-R9: four gll/LDS structures (barrier-drain, counted-vmcnt depth-1/3,
// register-window) pin at 86-91us with every pipe <40% busy. Round-10 tests the
// OTHER family at its best: R1's register-tiled no-LDS kernel with its locality
// bug fixed. R1 failed (FETCH 2x compulsory) because the co-resident grid spread
// the +-128-row reuse window across the whole matrix. Fix is pure mapping:
//   - xcd = bid & 7: each XCD owns a 128-f4 column stripe (2 KB/row) for the
//     full height -> all row-overlap reuse is XCD-local.
//   - w = bid >> 3 walks 64-row bands CONSECUTIVELY (dispatch-order = row order),
//     half-stripe (sub) walked sequentially -> active window ~4-10 MB, L2-first.
// Compute body = R1's verified one: TR=16 f4 accumulators/thread; far offsets
// (+-64,+-128) direct; near cluster {-8,-1,0,1,8} as a 32-row scatter pass (each
// input row loaded ONCE, feeds up to 5 accumulators) -> 96 loads / 16 outputs
// (6x amplification vs 9x naive). Diag row index is wave-uniform -> scalar loads.
// No LDS, no barriers, no gll, plain stores (R1's nontemporal inflated WRITE 18%).

#define DIA_N 8192
#define DIA_M 4096
#define M4    (DIA_M / 4)   // 1024 f4 per row
#define TRR   16            // rows per thread

typedef float f4 __attribute__((ext_vector_type(4)));

__global__ __launch_bounds__(256) void sparse_dia_kernel(
    const float* __restrict__ diags,   // [9, N]
    const float* __restrict__ other,   // [N, M]
    float* __restrict__ out)           // [N, M]
{
    // ---- XCD-pinned stripe mapping ----
    const int bid  = blockIdx.x;            // 0..2047
    const int xcd  = bid & 7;               // XCD round-robin heuristic
    const int w    = bid >> 3;              // 0..255: per-XCD walk index
    const int sub  = w >> 7;                // 0..1: 64-f4 half-stripe, walked 2nd
    const int band = w & 127;               // 0..127: 64-row band, consecutive
    const int lane = threadIdx.x & 63;
    const int slot = threadIdx.x >> 6;      // wave 0..3: 16-row slot within band

    const int r0 = band * 64 + slot * TRR;          // first output row (wave-uniform)
    const int c4 = xcd * 128 + sub * 64 + lane;     // this lane's f4 column

    const f4* __restrict__ o4   = (const f4*)other;
    f4* __restrict__       out4 = (f4*)out;

    f4 acc[TRR];
#pragma unroll
    for (int i = 0; i < TRR; ++i) acc[i] = (f4){0.f, 0.f, 0.f, 0.f};

    if (band >= 2 && band <= 125) {
        // ---- interior fast path: all taps in range ----

        // far offsets: no row overlap at TR=16; diag index wave-uniform -> s_load
        constexpr int FOFF[4] = {-128, -64, 64, 128};
        constexpr int FK[4]   = {0, 1, 7, 8};
#pragma unroll
        for (int f = 0; f < 4; ++f) {
#pragma unroll
            for (int i = 0; i < TRR; ++i) {
                const int q = r0 + i + FOFF[f];
                acc[i] += diags[FK[f] * DIA_N + q] * o4[(size_t)q * M4 + c4];
            }
        }

        // near cluster {-8,-1,0,1,8}: rows [r0-8, r0+TR+8) each loaded ONCE,
        // scattered into up to 5 accumulators (coef index = input row q).
#pragma unroll
        for (int j = -8; j < TRR + 8; ++j) {
            const int q = r0 + j;
            const f4 v  = o4[(size_t)q * M4 + c4];
            if (j + 8 >= 0 && j + 8 < TRR) acc[j + 8] += diags[2 * DIA_N + q] * v;  // -8
            if (j + 1 >= 0 && j + 1 < TRR) acc[j + 1] += diags[3 * DIA_N + q] * v;  // -1
            if (j     >= 0 && j     < TRR) acc[j    ] += diags[4 * DIA_N + q] * v;  //  0
            if (j - 1 >= 0 && j - 1 < TRR) acc[j - 1] += diags[5 * DIA_N + q] * v;  // +1
            if (j - 8 >= 0 && j - 8 < TRR) acc[j - 8] += diags[6 * DIA_N + q] * v;  // +8
        }
    } else {
        // ---- edge bands (0,1,126,127): guard every tap ----
        constexpr int OFF[9] = {-128, -64, -8, -1, 0, 1, 8, 64, 128};
#pragma unroll
        for (int k = 0; k < 9; ++k) {
#pragma unroll
            for (int i = 0; i < TRR; ++i) {
                const int q = r0 + i + OFF[k];
                if (q >= 0 && q < DIA_N)
                    acc[i] += diags[k * DIA_N + q] * o4[(size_t)q * M4 + c4];
            }
        }
    }

#pragma unroll
    for (int i = 0; i < TRR; ++i)
        out4[(size_t)(r0 + i) * M4 + c4] = acc[i];
}

extern "C" void kernel_launch(void* const* d_in, const int* in_sizes, int n_in,
                              void* d_out, int out_size, void* d_ws, size_t ws_size,
                              hipStream_t stream) {
    const float* diags = (const float*)d_in[0];   // 9 * 8192 fp32
    const float* other = (const float*)d_in[1];   // 8192 * 4096 fp32
    float* out         = (float*)d_out;           // 8192 * 4096 fp32

    // 2048 blocks x 256 threads; 1D grid so the bid->XCD round-robin and the
    // per-XCD row walk are explicit in the mapping above.
    dim3 block(256, 1, 1);
    dim3 grid(2048, 1, 1);
    sparse_dia_kernel<<<grid, block, 0, stream>>>(diags, other, out);
}

// Round 11
// 242.240 us; speedup vs baseline: 1.1412x; 1.1412x over previous
//
#include <hip/hip_runtime.h>

// SparseDIA (9 static offsets) @ dense: out[r,c] = sum_k diags[k, r+off_k] * other[r+off_k, c]
// N=8192, M=4096, fp32.
//
// Round-11: exact copy of R5 (best measured: 85.5-87.3us/dispatch) with ONE change:
// __builtin_nontemporal_store for out. Theory: the universal ~86us pin across all
// five structural families is the L3/HBM write path -- other(134MB)+out(134MB) =
// 268MB > 256MB L3, so every out-line allocation evicts `other`, re-fetched from
// HBM each iteration (steady-state FETCH ~72MB), and the measured write rate caps
// at 1.1-1.55 TB/s in EVERY round. nt stores bypass L3 allocation: out streams to
// HBM, `other` stays fully L3-resident, read/write paths decouple.
//
// Structure (= R5): grid 128 col-stripes x 4 row-groups = 512 blocks (2/CU),
// 1024 thr (16 waves), ring 512 rows x 128 B = 64 KB + 2x4.5 KB diag slices.
// Per band: {issue gll chunk t+1 + diags t+1 -> compute band t from LDS ->
// __syncthreads}. Both-sides XOR bank swizzle col^(s&7) (proven 2-way/free).

#define DIA_N   8192
#define DIA_M   4096
#define M4      (DIA_M / 4)   // 1024 float4 per row
#define CB      8             // float4 cols per block (128 B stripe)
#define BR      128           // rows per band
#define HALO    128           // max |offset|
#define RING    512           // ring rows = 2*BR + 2*HALO (power of 2)
#define NB      16            // bands per block
#define GROUP   (BR * NB)     // 2048 rows per block
#define THREADS 1024
#define NWAVES  (THREADS / 64)

typedef float f4 __attribute__((ext_vector_type(4)));
typedef __attribute__((address_space(3))) unsigned int       lds_uint;
typedef const __attribute__((address_space(1))) unsigned int glb_uint;

__global__ __launch_bounds__(THREADS, 8) void sparse_dia_kernel(
    const float* __restrict__ diags,   // [9, N]
    const float* __restrict__ other,   // [N, M]
    float* __restrict__ out)           // [N, M]
{
    constexpr int OFF[9] = {-128, -64, -8, -1, 0, 1, 8, 64, 128};

    __shared__ f4    ring[RING][CB];     // 64 KB, rows linear (gll dest), cols XOR-swizzled
    __shared__ float dlds[2][9 * BR];    // 2 x 4.5 KB zero-padded diag slices

    const int tid  = threadIdx.x;
    const int gr0  = blockIdx.y * GROUP;        // first output row of this block
    const int cb4  = blockIdx.x * CB;           // first float4 column

    const int wave = tid >> 6;
    const int lane = tid & 63;
    const int lrow = lane >> 3;                 // 0..7: row within an 8-row gll chunk
    const int lcol = lane & 7;                  // 0..7: LDS col slot this lane fills
    // Both-sides swizzle: LDS position (row, lcol) must hold global col lcol^(row&7).
    // Chunk base rows are always ==0 mod 8, so row&7 == lrow.
    const int scol = lcol ^ lrow;               // pre-swizzled GLOBAL source column

    // ---- stage ring rows: one gll instr = 8 rows x 128 B = 1 KB (linear dest) ----
    auto stage_ring = [&](int slot0, int q0, int ninst) {
#pragma unroll
        for (int s = 0; s < 3; ++s) {           // max ninst = 3 (prologue)
            if (s >= ninst) break;
            const int inst = wave * ninst + s;
            int q = q0 + inst * 8 + lrow;
            q = (q < 0) ? 0 : (q >= DIA_N ? DIA_N - 1 : q);  // clamp; diag=0 kills garbage
            const float* src = other + ((size_t)q * DIA_M + (size_t)(cb4 + scol) * 4);
            __builtin_amdgcn_global_load_lds(
                (glb_uint*)src,
                (lds_uint*)&ring[slot0 + inst * 8][0],        // wave-uniform base
                16, 0, 0);
        }
    };

    // ---- stage zero-padded diag slice for band t into dlds[buf] ----
    auto stage_diag = [&](int buf, int t) {
        const int bs = gr0 + t * BR;            // band's first output row
        for (int f = tid; f < 9 * BR; f += THREADS) {
            const int k  = f >> 7;              // BR = 128
            const int i  = f & (BR - 1);
            const int q  = bs + i + OFF[k];
            const int qc = (q < 0) ? 0 : (q >= DIA_N ? DIA_N - 1 : q);
            float v = diags[k * DIA_N + qc];    // branchless: always-safe load
            v = ((unsigned)q < (unsigned)DIA_N) ? v : 0.f;
            dlds[buf][f] = v;
        }
    };

    f4* __restrict__ out4 = (f4*)out;

    // ---- prologue: band-0 live window = logical rows [0, 384) = 48 gll instrs ----
    stage_ring(0, gr0 - HALO, 3);
    stage_diag(0, 0);
    __syncthreads();

    const int c = tid & 7;                      // f4 col
    const int i = tid >> 3;                     // band row, 0..127 (1 row/thread)

    for (int t = 0; t < NB; ++t) {
        // issue next chunk + next diags BEFORE computing (overlap with compute).
        if (t + 1 < NB) {
            const int u = (BR + 2 * HALO) + t * BR;
            stage_ring(u & (RING - 1), gr0 - HALO + u, 1);
            stage_diag((t + 1) & 1, t + 1);
        }

        // ---- compute band t purely from LDS ----
        const int buf  = t & 1;
        const int base = (HALO + t * BR) & (RING - 1);  // ring slot of band row 0

        float dk[9];
#pragma unroll
        for (int k = 0; k < 9; ++k) dk[k] = dlds[buf][k * BR + i];  // 8-lane broadcast

        f4 a = (f4){0.f, 0.f, 0.f, 0.f};
#pragma unroll
        for (int k = 0; k < 9; ++k) {
            const int slot = (base + i + OFF[k]) & (RING - 1);
            a += dk[k] * ring[slot][c ^ (slot & 7)];    // swizzled read
        }

        // THE ONE CHANGE vs R5: nontemporal store -> no L3 allocation for out,
        // so `other` (134 MB < 256 MB) stays L3-resident; write stream decouples.
        __builtin_nontemporal_store(a,
            &out4[(size_t)(gr0 + t * BR + i) * M4 + cb4 + c]);

        __syncthreads();
    }
}

extern "C" void kernel_launch(void* const* d_in, const int* in_sizes, int n_in,
                              void* d_out, int out_size, void* d_ws, size_t ws_size,
                              hipStream_t stream) {
    const float* diags = (const float*)d_in[0];   // 9 * 8192 fp32
    const float* other = (const float*)d_in[1];   // 8192 * 4096 fp32
    float* out         = (float*)d_out;           // 8192 * 4096 fp32

    // 512 blocks = 2/CU (73 KB LDS each), 16 waves each -> 32 waves/CU.
    dim3 block(THREADS, 1, 1);
    dim3 grid(M4 / CB, DIA_N / GROUP, 1);         // (128, 4)
    sparse_dia_kernel<<<grid, block, 0, stream>>>(diags, other, out);
}